// Round 7
// baseline (112.442 us; speedup 1.0000x reference)
//
#include <hip/hip_runtime.h>

// CatNet_76553497084407 — SLAYER-style spiking CNN, fully collapsed over time.
//
// R14: halve DS wave-instructions again. The validated law across 8 rounds:
// time responds to memory-pipe ISSUE SLOTS (R9 +DS->+16%, R12 +VMEM->+170%,
// R13 -75% DS inst -> -15%), not to stalls/conflicts/TLP (R8, R11 null).
// Window ds_read_b128s amortize over out-channels per thread, so move from
// 4 oc/thread to 8 oc/thread in phases 2 and 4:
//   * phase 2: 4 groups x 128 thr (waves 0-7), thread = 2h x 8oc.
//     DS/CU 640 -> ~336 wave-inst; VALU wall unchanged (2 waves/SIMD x 2x FMA).
//   * phase 4: 8 waves = 4 oc-groups x 2 h-halves, thread = 1h x 8oc.
//     DS/CU 896 -> ~512. 1-deep quad prefetch kept (~84 VGPR < 128 budget).
//   * per-output accumulation order unchanged -> bit-identical (absmax 0.0).
//   * weights stay wave-uniform s_load (R9: LDS-staging +16%; R12: per-lane
//     weight addrs -> vector loads, +170%).
// R13 kept: ci-quad float4 interstage layouts (r1qe/r1qo/r3q), exact c/50
// LDS rate table, 2e-4 risky threshold, no-ballot pooled rate, float2 ph 0/5.
// Spill tripwire: WRITE_SIZE must stay ~tens of KB (spills were 190MB+).

#define T_STEPS 50
#define THETA   0.9999f

// component of a float4 by compile-time index (folds after unroll)
#define F4C(v, c) ((c) == 0 ? (v).x : (c) == 1 ? (v).y : (c) == 2 ? (v).z : (v).w)

// Exact-rounding rate: tbl[c] == c/50.0f computed with a true divide once.
__device__ __forceinline__ float spike_rate(float a, const float* __restrict__ tbl) {
    constexpr float INV = 50.0f / 0.9999f;
    float t = a * INV;
    float c = fminf(fmaxf(floorf(t), 0.0f), 50.0f);
    // fall back to the exact 50-step f32 sim when t is near an integer
    bool risky = (t > 0.5f) && (fabsf(t - rintf(t)) < 2e-4f);
    if (__ballot(risky)) {
        float v = 0.f, cnt = 0.f;
#pragma unroll 1
        for (int k = 0; k < T_STEPS; ++k) {
            v += a;
            float s = (v >= THETA) ? 1.0f : 0.0f;
            v -= s * THETA;
            cnt += s;
        }
        c = cnt;
    }
    return tbl[(int)c];
}

// No-ballot variant: only legal when the input provably cannot sit within
// 2e-4 of an integer boundary in t-units (pooled path: 1.1*k/50, margin 1.1e-3).
__device__ __forceinline__ float spike_rate_nb(float a, const float* __restrict__ tbl) {
    constexpr float INV = 50.0f / 0.9999f;
    float t = a * INV;
    float c = fminf(fmaxf(floorf(t), 0.0f), 50.0f);
    return tbl[(int)c];
}

extern "C" __global__ void __launch_bounds__(1024, 4)
catnet_kernel(const float* __restrict__ x,
              const float* __restrict__ w1, const float* __restrict__ b1,
              const float* __restrict__ w2, const float* __restrict__ b2,
              const float* __restrict__ w3, const float* __restrict__ b3,
              const float* __restrict__ wf, const float* __restrict__ bf,
              float* __restrict__ out)
{
    const int n    = blockIdx.x;
    const int tid  = threadIdx.x;
    const int wave = tid >> 6;
    const int lane = tid & 63;

    __shared__ float  xbar[182];        // [h+1], h in [0,180)
    __shared__ float4 r1qe[4][92];      // [ciq][i] = conv1 rate at even padded H=2i, ci quad
    __shared__ float4 r1qo[4][92];      // [ciq][i] = odd padded H=2i+1
    __shared__ float4 r3q[8][89];       // [ciq][p+1] = pooled rate, ci quad
    __shared__ alignas(16) float r4s[32][83];
    __shared__ float  ratetbl[51];      // exact c/50.0f
    __shared__ float  part[16];

    // zero conv pads + build exact-rate table
    const float4 z4 = make_float4(0.f, 0.f, 0.f, 0.f);
    if (tid < 4)               r1qe[tid][0]       = z4;   // H=0 pad
    if (tid >= 4  && tid < 8)  r1qo[tid - 4][90]  = z4;   // H=181 pad
    if (tid >= 8  && tid < 16) r3q[tid - 8][0]    = z4;   // p_idx=0 pad
    if (tid >= 16 && tid < 24) r3q[tid - 16][88]  = z4;   // p_idx=88 pad
    if (tid == 64)             { xbar[0] = 0.f; xbar[181] = 0.f; }
    if (tid >= 128 && tid < 179) ratetbl[tid - 128] = (float)(tid - 128) / 50.0f;

    // ---- phase 0: time-sum of input, 4 lanes per h, float2 loads ----
    const float* xn = x + (size_t)n * (180 * 50);
    if (tid < 720) {
        const int h = tid >> 2, q = tid & 3;
        const float2* row2 = reinterpret_cast<const float2*>(xn + h * 50);
        float s = 0.f;
        for (int k = q; k < 24; k += 4) { float2 v = row2[k]; s += v.x + v.y; }
        if (q == 0)                     { float2 v = row2[24]; s += v.x + v.y; }
        s += __shfl_xor(s, 1, 4);
        s += __shfl_xor(s, 2, 4);
        if (q == 0) xbar[h + 1] = s;
    }
    __syncthreads();

    // ---- phase 1: conv1 (1->16, k=3, pad=1), /T, +b1, rate ----
    for (int idx = tid; idx < 16 * 180; idx += 1024) {
        int c = idx / 180, h = idx - c * 180;
        float a = w1[c*3+0] * xbar[h] + w1[c*3+1] * xbar[h+1] + w1[c*3+2] * xbar[h+2];
        a = a / 50.0f + b1[c];
        float r = spike_rate(a, ratetbl);
        int H = h + 1;
        float* dst = (H & 1) ? (float*)&r1qo[c >> 2][H >> 1]
                             : (float*)&r1qe[c >> 2][H >> 1];
        dst[c & 3] = r;
    }
    __syncthreads();

    // ---- phase 2: conv2 (16->32, k=9, pad=1) + rate + pool(2)*1.1 + rate ----
    // 4 groups of 128 threads (waves 0-7 only): g = tid>>7, p = tid&127 < 87.
    // Thread computes conv2 at h=2p,2p+1 (shared 10-tap window) for 8 out-ch.
    // Per ci-quad: 10 ds_read_b128 amortized over 8 oc (was 4).
    if (tid < 512) {
        const int g   = __builtin_amdgcn_readfirstlane(tid >> 7);   // 0..3
        const int p   = tid & 127;
        const bool act = p < 87;
        const int pr  = act ? p : 0;
        const float* wb = w2 + g * 8 * 144;   // [oc][ci][kh], oc stride 144

        float a0[8], a1[8];
#pragma unroll
        for (int j = 0; j < 8; ++j) { a0[j] = b2[g*8 + j]; a1[j] = a0[j]; }

#pragma unroll 1
        for (int qd = 0; qd < 4; ++qd) {
            float4 we[5], wo[5];
#pragma unroll
            for (int d = 0; d < 5; ++d) { we[d] = r1qe[qd][pr + d]; wo[d] = r1qo[qd][pr + d]; }

#pragma unroll
            for (int c4 = 0; c4 < 4; ++c4) {
                const int ci = qd * 4 + c4;
#pragma unroll
                for (int j = 0; j < 8; ++j) {
                    const float* wj = wb + j * 144 + ci * 9;
#pragma unroll
                    for (int kh = 0; kh < 9; ++kh) {
                        float wv  = wj[kh];
                        float xlo = (kh & 1) ? F4C(wo[kh >> 1], c4)
                                             : F4C(we[kh >> 1], c4);        // tap kh
                        float xhi = (kh & 1) ? F4C(we[(kh + 1) >> 1], c4)
                                             : F4C(wo[kh >> 1], c4);        // tap kh+1
                        a0[j] += wv * xlo;     // h = 2p
                        a1[j] += wv * xhi;     // h = 2p+1
                    }
                }
            }
        }
        float r3t[8];
#pragma unroll
        for (int j = 0; j < 8; ++j) {
            float r20 = spike_rate(a0[j], ratetbl);
            float r21 = spike_rate(a1[j], ratetbl);
            r3t[j] = spike_rate_nb(1.1f * (r20 + r21), ratetbl);
        }
        if (act) {
            r3q[g*2][p + 1]     = make_float4(r3t[0], r3t[1], r3t[2], r3t[3]);
            r3q[g*2 + 1][p + 1] = make_float4(r3t[4], r3t[5], r3t[6], r3t[7]);
        }
    }
    __syncthreads();

    // ---- phase 4: conv3 (32->32, k=7, pad=1) + rate ----
    // 8 waves = 4 oc-groups(8) x 2 h-halves; lanes -> h. Per ci-quad: 7
    // ds_read_b128 amortized over 8 oc (was 4); 1-deep quad prefetch.
    if (tid < 512) {
        const int gg   = __builtin_amdgcn_readfirstlane(wave >> 1);  // 0..3
        const int g8   = gg * 8;
        const int half = wave & 1;
        const int cnt  = half ? 41 : 42;
        const bool act = lane < cnt;
        const int h0   = half * 42 + lane;    // valid max 82; window max 88
        const int hr   = act ? h0 : 0;
        const float* wb = w3 + g8 * 224;      // [oc][ci][kh], oc stride 224

        float a[8];
#pragma unroll
        for (int j = 0; j < 8; ++j) a[j] = b3[g8 + j];

        float4 rv[7];
#pragma unroll
        for (int d = 0; d < 7; ++d) rv[d] = r3q[0][hr + d];

#pragma unroll 1
        for (int q = 0; q < 8; ++q) {
            const int qn = (q < 7) ? q + 1 : 7;
            float4 rn[7];
#pragma unroll
            for (int d = 0; d < 7; ++d) rn[d] = r3q[qn][hr + d];

#pragma unroll
            for (int c4 = 0; c4 < 4; ++c4) {
                const int ci = q * 4 + c4;
#pragma unroll
                for (int j = 0; j < 8; ++j) {
                    const float* wj = wb + j * 224 + ci * 7;
#pragma unroll
                    for (int kh = 0; kh < 7; ++kh)
                        a[j] += wj[kh] * F4C(rv[kh], c4);
                }
            }
#pragma unroll
            for (int d = 0; d < 7; ++d) rv[d] = rn[d];
        }
#pragma unroll
        for (int j = 0; j < 8; ++j) {
            float r = spike_rate(a[j], ratetbl);
            if (act) r4s[g8 + j][h0] = r;
        }
    }
    __syncthreads();

    // ---- phase 5: dense [32*83] -> 4 outputs; 4 waves per output, float2 ----
    {
        const int o = wave >> 2, q = wave & 3;
        const float2* r42 = reinterpret_cast<const float2*>(&r4s[0][0]);
        const float2* wo2 = reinterpret_cast<const float2*>(wf + o * (32 * 83));
        float acc = 0.f;
        for (int j = q * 64 + lane; j < 1328; j += 256) {
            float2 rv = r42[j], wv = wo2[j];
            acc += rv.x * wv.x + rv.y * wv.y;
        }
#pragma unroll
        for (int off = 32; off > 0; off >>= 1)
            acc += __shfl_down(acc, off, 64);
        if (lane == 0) part[wave] = acc;
    }
    __syncthreads();
    if (tid < 4) {
        float s = part[tid*4] + part[tid*4+1] + part[tid*4+2] + part[tid*4+3];
        out[n * 4 + tid] = s + bf[tid];
    }
}

extern "C" void kernel_launch(void* const* d_in, const int* in_sizes, int n_in,
                              void* d_out, int out_size, void* d_ws, size_t ws_size,
                              hipStream_t stream) {
    const float* x  = (const float*)d_in[0];
    const float* w1 = (const float*)d_in[1];
    const float* b1 = (const float*)d_in[2];
    const float* w2 = (const float*)d_in[3];
    const float* b2 = (const float*)d_in[4];
    const float* w3 = (const float*)d_in[5];
    const float* b3 = (const float*)d_in[6];
    const float* wf = (const float*)d_in[7];
    const float* bf = (const float*)d_in[8];
    float* outp = (float*)d_out;

    catnet_kernel<<<dim3(256), dim3(1024), 0, stream>>>(
        x, w1, b1, w2, b2, w3, b3, wf, bf, outp);
}

// Round 8
// 100.173 us; speedup vs baseline: 1.1225x; 1.1225x over previous
//
#include <hip/hip_runtime.h>

// CatNet_76553497084407 — SLAYER-style spiking CNN, fully collapsed over time.
//
// R15 = R13 (best: 99.2us bench, kernel ~35us, absmax 0.0) + 1-deep tap
// prefetch in the conv loops. R14 lesson: DS-slot cuts that idle waves lose
// (halving active waves halved VALUBusy, +9us) -> R13's all-16-wave mapping
// is the DS/TLP sweet spot; revert to it exactly.
//
// The validated law: time tracks memory-pipe ISSUE SLOTS (R9 +DS->+16%,
// R12 +VMEM->+170%, R13 -75% DS->-15%) while stall/conflict/TLP tweaks are
// null (R8, R11) and idle-wave trades are negative (R14).
// R13 residual: VALU ~19k cyc/SIMD, DS ~18k cyc/CU, wall ~84k cyc -> both
// pipes <25% busy; the rest is ds_read->FMA dependency latency per quad
// iteration (10/7 b128 reads, ~120cyc, then 288/448 FMA). R13 had no
// prefetch; at 44 VGPR under bounds(1024,4) (budget 128) a 1-deep prefetch
// can now materialize (R8's was folded away at the 32-VGPR cap).
//   * phase 2: prefetch next ci-quad's 10 taps (weN/woN) before FMA block.
//   * phase 4: prefetch next quad's 7 taps (rn) before FMA block.
//   * accumulation order per output unchanged -> expect absmax 0.0 again.
//   * weights stay wave-uniform s_load (R9/R12 lessons).
// Spill tripwire: WRITE_SIZE must stay ~tens of KB (spills were 190MB+).

#define T_STEPS 50
#define THETA   0.9999f

// component of a float4 by compile-time index (folds after unroll)
#define F4C(v, c) ((c) == 0 ? (v).x : (c) == 1 ? (v).y : (c) == 2 ? (v).z : (v).w)

// Exact-rounding rate: tbl[c] == c/50.0f computed with a true divide once.
__device__ __forceinline__ float spike_rate(float a, const float* __restrict__ tbl) {
    constexpr float INV = 50.0f / 0.9999f;
    float t = a * INV;
    float c = fminf(fmaxf(floorf(t), 0.0f), 50.0f);
    // fall back to the exact 50-step f32 sim when t is near an integer
    bool risky = (t > 0.5f) && (fabsf(t - rintf(t)) < 2e-4f);
    if (__ballot(risky)) {
        float v = 0.f, cnt = 0.f;
#pragma unroll 1
        for (int k = 0; k < T_STEPS; ++k) {
            v += a;
            float s = (v >= THETA) ? 1.0f : 0.0f;
            v -= s * THETA;
            cnt += s;
        }
        c = cnt;
    }
    return tbl[(int)c];
}

// No-ballot variant: only legal when the input provably cannot sit within
// 2e-4 of an integer boundary in t-units (pooled path: 1.1*k/50, margin 1.1e-3).
__device__ __forceinline__ float spike_rate_nb(float a, const float* __restrict__ tbl) {
    constexpr float INV = 50.0f / 0.9999f;
    float t = a * INV;
    float c = fminf(fmaxf(floorf(t), 0.0f), 50.0f);
    return tbl[(int)c];
}

extern "C" __global__ void __launch_bounds__(1024, 4)
catnet_kernel(const float* __restrict__ x,
              const float* __restrict__ w1, const float* __restrict__ b1,
              const float* __restrict__ w2, const float* __restrict__ b2,
              const float* __restrict__ w3, const float* __restrict__ b3,
              const float* __restrict__ wf, const float* __restrict__ bf,
              float* __restrict__ out)
{
    const int n    = blockIdx.x;
    const int tid  = threadIdx.x;
    const int wave = tid >> 6;
    const int lane = tid & 63;

    __shared__ float  xbar[182];        // [h+1], h in [0,180)
    __shared__ float4 r1qe[4][92];      // [ciq][i] = conv1 rate at even padded H=2i, ci quad
    __shared__ float4 r1qo[4][92];      // [ciq][i] = odd padded H=2i+1
    __shared__ float4 r3q[8][89];       // [ciq][p+1] = pooled rate, ci quad
    __shared__ alignas(16) float r4s[32][83];
    __shared__ float  ratetbl[51];      // exact c/50.0f
    __shared__ float  part[16];

    // zero conv pads + build exact-rate table
    const float4 z4 = make_float4(0.f, 0.f, 0.f, 0.f);
    if (tid < 4)               r1qe[tid][0]       = z4;   // H=0 pad
    if (tid >= 4  && tid < 8)  r1qo[tid - 4][90]  = z4;   // H=181 pad
    if (tid >= 8  && tid < 16) r3q[tid - 8][0]    = z4;   // p_idx=0 pad
    if (tid >= 16 && tid < 24) r3q[tid - 16][88]  = z4;   // p_idx=88 pad
    if (tid == 64)             { xbar[0] = 0.f; xbar[181] = 0.f; }
    if (tid >= 128 && tid < 179) ratetbl[tid - 128] = (float)(tid - 128) / 50.0f;

    // ---- phase 0: time-sum of input, 4 lanes per h, float2 loads ----
    const float* xn = x + (size_t)n * (180 * 50);
    if (tid < 720) {
        const int h = tid >> 2, q = tid & 3;
        const float2* row2 = reinterpret_cast<const float2*>(xn + h * 50);
        float s = 0.f;
        for (int k = q; k < 24; k += 4) { float2 v = row2[k]; s += v.x + v.y; }
        if (q == 0)                     { float2 v = row2[24]; s += v.x + v.y; }
        s += __shfl_xor(s, 1, 4);
        s += __shfl_xor(s, 2, 4);
        if (q == 0) xbar[h + 1] = s;
    }
    __syncthreads();

    // ---- phase 1: conv1 (1->16, k=3, pad=1), /T, +b1, rate ----
    for (int idx = tid; idx < 16 * 180; idx += 1024) {
        int c = idx / 180, h = idx - c * 180;
        float a = w1[c*3+0] * xbar[h] + w1[c*3+1] * xbar[h+1] + w1[c*3+2] * xbar[h+2];
        a = a / 50.0f + b1[c];
        float r = spike_rate(a, ratetbl);
        int H = h + 1;
        float* dst = (H & 1) ? (float*)&r1qo[c >> 2][H >> 1]
                             : (float*)&r1qe[c >> 2][H >> 1];
        dst[c & 3] = r;
    }
    __syncthreads();

    // ---- phase 2: conv2 (16->32, k=9, pad=1) + rate + pool(2)*1.1 + rate ----
    // 8 groups of 128 threads: g = tid>>7 (wave-uniform), p = tid&127 < 87.
    // Thread computes conv2 at h=2p,2p+1 (shared 10-tap window) for 4 out-ch.
    // Per ci-quad: 10 ds_read_b128 window taps; next quad's taps prefetched
    // 1-deep so the ~120cyc ds latency hides behind the 288-FMA block.
    {
        const int g   = __builtin_amdgcn_readfirstlane(tid >> 7);   // 0..7
        const int p   = tid & 127;
        const bool act = p < 87;
        const int pr  = act ? p : 0;
        const float* wb = w2 + g * 4 * 144;   // [oc][ci][kh], oc stride 144

        float a0[4], a1[4];
#pragma unroll
        for (int j = 0; j < 4; ++j) { a0[j] = b2[g*4 + j]; a1[j] = a0[j]; }

        float4 we[5], wo[5];
#pragma unroll
        for (int d = 0; d < 5; ++d) { we[d] = r1qe[0][pr + d]; wo[d] = r1qo[0][pr + d]; }

#pragma unroll 1
        for (int qd = 0; qd < 4; ++qd) {
            const int qn = (qd < 3) ? qd + 1 : 3;   // clamp: last iter re-reads
            float4 weN[5], woN[5];
#pragma unroll
            for (int d = 0; d < 5; ++d) { weN[d] = r1qe[qn][pr + d]; woN[d] = r1qo[qn][pr + d]; }

#pragma unroll
            for (int c4 = 0; c4 < 4; ++c4) {
                const int ci = qd * 4 + c4;
#pragma unroll
                for (int j = 0; j < 4; ++j) {
                    const float* wj = wb + j * 144 + ci * 9;
#pragma unroll
                    for (int kh = 0; kh < 9; ++kh) {
                        float wv  = wj[kh];
                        float xlo = (kh & 1) ? F4C(wo[kh >> 1], c4)
                                             : F4C(we[kh >> 1], c4);        // tap kh
                        float xhi = (kh & 1) ? F4C(we[(kh + 1) >> 1], c4)
                                             : F4C(wo[kh >> 1], c4);        // tap kh+1
                        a0[j] += wv * xlo;     // h = 2p
                        a1[j] += wv * xhi;     // h = 2p+1
                    }
                }
            }
#pragma unroll
            for (int d = 0; d < 5; ++d) { we[d] = weN[d]; wo[d] = woN[d]; }
        }
        float r3t[4];
#pragma unroll
        for (int j = 0; j < 4; ++j) {
            float r20 = spike_rate(a0[j], ratetbl);
            float r21 = spike_rate(a1[j], ratetbl);
            r3t[j] = spike_rate_nb(1.1f * (r20 + r21), ratetbl);
        }
        if (act) r3q[g][p + 1] = make_float4(r3t[0], r3t[1], r3t[2], r3t[3]);
    }
    __syncthreads();

    // ---- phase 4: conv3 (32->32, k=7, pad=1) + rate ----
    // 16 waves = 8 out-ch-groups(4) x 2 h-halves; lanes -> h.
    // Per ci-quad: 7 ds_read_b128 window taps, 1-deep prefetch.
    {
        const int gg   = __builtin_amdgcn_readfirstlane(wave >> 1);  // 0..7
        const int g4   = gg * 4;
        const int half = wave & 1;
        const int cnt  = half ? 41 : 42;
        const bool act = lane < cnt;
        const int h0   = half * 42 + lane;    // valid max 82; window max 88
        const int hr   = act ? h0 : 0;
        const float* wb = w3 + g4 * 224;      // [oc][ci][kh], oc stride 224

        float a[4];
#pragma unroll
        for (int j = 0; j < 4; ++j) a[j] = b3[g4 + j];

        float4 rv[7];
#pragma unroll
        for (int d = 0; d < 7; ++d) rv[d] = r3q[0][hr + d];

#pragma unroll 1
        for (int q = 0; q < 8; ++q) {
            const int qn = (q < 7) ? q + 1 : 7;
            float4 rn[7];
#pragma unroll
            for (int d = 0; d < 7; ++d) rn[d] = r3q[qn][hr + d];

#pragma unroll
            for (int c4 = 0; c4 < 4; ++c4) {
                const int ci = q * 4 + c4;
#pragma unroll
                for (int j = 0; j < 4; ++j) {
                    const float* wj = wb + j * 224 + ci * 7;
#pragma unroll
                    for (int kh = 0; kh < 7; ++kh)
                        a[j] += wj[kh] * F4C(rv[kh], c4);
                }
            }
#pragma unroll
            for (int d = 0; d < 7; ++d) rv[d] = rn[d];
        }
#pragma unroll
        for (int j = 0; j < 4; ++j) {
            float r = spike_rate(a[j], ratetbl);
            if (act) r4s[g4 + j][h0] = r;
        }
    }
    __syncthreads();

    // ---- phase 5: dense [32*83] -> 4 outputs; 4 waves per output, float2 ----
    {
        const int o = wave >> 2, q = wave & 3;
        const float2* r42 = reinterpret_cast<const float2*>(&r4s[0][0]);
        const float2* wo2 = reinterpret_cast<const float2*>(wf + o * (32 * 83));
        float acc = 0.f;
        for (int j = q * 64 + lane; j < 1328; j += 256) {
            float2 rv = r42[j], wv = wo2[j];
            acc += rv.x * wv.x + rv.y * wv.y;
        }
#pragma unroll
        for (int off = 32; off > 0; off >>= 1)
            acc += __shfl_down(acc, off, 64);
        if (lane == 0) part[wave] = acc;
    }
    __syncthreads();
    if (tid < 4) {
        float s = part[tid*4] + part[tid*4+1] + part[tid*4+2] + part[tid*4+3];
        out[n * 4 + tid] = s + bf[tid];
    }
}

extern "C" void kernel_launch(void* const* d_in, const int* in_sizes, int n_in,
                              void* d_out, int out_size, void* d_ws, size_t ws_size,
                              hipStream_t stream) {
    const float* x  = (const float*)d_in[0];
    const float* w1 = (const float*)d_in[1];
    const float* b1 = (const float*)d_in[2];
    const float* w2 = (const float*)d_in[3];
    const float* b2 = (const float*)d_in[4];
    const float* w3 = (const float*)d_in[5];
    const float* b3 = (const float*)d_in[6];
    const float* wf = (const float*)d_in[7];
    const float* bf = (const float*)d_in[8];
    float* outp = (float*)d_out;

    catnet_kernel<<<dim3(256), dim3(1024), 0, stream>>>(
        x, w1, b1, w2, b2, w3, b3, wf, bf, outp);
}